// Round 9
// baseline (207.628 us; speedup 1.0000x reference)
//
#include <hip/hip_runtime.h>
#include <hip/hip_bf16.h>

// Emformer attention, MI355X. Sizes fixed by the problem.
#define EMBED   1024
#define NHEADS  16
#define HDIM    64
#define U_LEN   2048
#define R_LEN   256
#define L_LEN   1024
#define M_LEN   512
#define Q_LEN   (U_LEN + R_LEN)                 // 2304
#define KV_LEN  (M_LEN + R_LEN + L_LEN + U_LEN) // 3840
#define X_ROWS  (M_LEN + R_LEN + U_LEN)         // 2816
#define NPART   3
#define KV_PART (KV_LEN / NPART)                // 1280

typedef __attribute__((ext_vector_type(8))) short short8;
typedef __attribute__((ext_vector_type(4))) float f32x4;
typedef __attribute__((ext_vector_type(16))) float f32x16;

#define QSCALE 0.180336880f  /* 0.125 * log2(e): exp() via exp2(), implicit max=0 */

__device__ __forceinline__ void gl2lds16(const __hip_bfloat16* g, __hip_bfloat16* l) {
  __builtin_amdgcn_global_load_lds(
      (const __attribute__((address_space(1))) unsigned int*)g,
      (__attribute__((address_space(3))) unsigned int*)l, 16, 0, 0);
}

// bf16 pack via v_cvt_pk_bf16_f32 (RNE, 1 instr).
__device__ __forceinline__ unsigned pack_bf16(float a, float b) {
  unsigned r;
  asm("v_cvt_pk_bf16_f32 %0, %1, %2" : "=v"(r) : "v"(a), "v"(b));
  return r;
}

// Exchange: lo = {lane<32: a(own), lane>=32: b(partner)};
//           hi = {lane<32: a(partner), lane>=32: b(own)}.
__device__ __forceinline__ void plane_swap(unsigned a, unsigned b, int h2,
                                           unsigned& lo, unsigned& hi) {
#if __has_builtin(__builtin_amdgcn_permlane32_swap)
  auto r = __builtin_amdgcn_permlane32_swap(a, b, false, false);
  lo = r[0]; hi = r[1];
#else
  unsigned s0 = h2 ? a : b;
  unsigned r0 = __shfl_xor(s0, 32, 64);
  lo = h2 ? r0 : a;
  hi = h2 ? b : r0;
#endif
}

// ---------------------------------------------------------------- prep
// One kernel, block-range dispatched:
// [0,2816)      build X = bf16([memory; rc; utterance])
// [2816,3840)   Wq  -> WB rows 0..1023
// [3840,5888)   Wkv -> WB rows 1024..3071
// [5888,6912)   Wo  -> Wo_bf
// [6912,7936)   left-context insert (f32 key/value rows 768..1791 + bf16 K,V)
__global__ __launch_bounds__(256) void prep_kernel(
    const float* __restrict__ mem, const float* __restrict__ rc,
    const float* __restrict__ utt, const float* __restrict__ lk,
    const float* __restrict__ lv, const float* __restrict__ Wq,
    const float* __restrict__ Wkv, const float* __restrict__ Wo,
    __hip_bfloat16* __restrict__ X, __hip_bfloat16* __restrict__ WB,
    __hip_bfloat16* __restrict__ WoB,
    float* __restrict__ key_out, float* __restrict__ val_out,
    __hip_bfloat16* __restrict__ k_bf, __hip_bfloat16* __restrict__ v_bf) {
  int b = blockIdx.x, tid = threadIdx.x;
  if (b < 2816) {
    int row = b, col = tid * 4;
    const float* src;
    if (row < M_LEN)              src = mem + row * EMBED;
    else if (row < M_LEN + R_LEN) src = rc + (row - M_LEN) * EMBED;
    else                          src = utt + (row - M_LEN - R_LEN) * EMBED;
    float4 v = *reinterpret_cast<const float4*>(src + col);
    uint2 pk; pk.x = pack_bf16(v.x, v.y); pk.y = pack_bf16(v.z, v.w);
    *reinterpret_cast<uint2*>(X + (size_t)row * EMBED + col) = pk;
  } else if (b < 6912) {
    const float* src; __hip_bfloat16* dst;
    int blk;
    if (b < 3840)      { src = Wq;  dst = WB;                blk = b - 2816; }
    else if (b < 5888) { src = Wkv; dst = WB + 1024 * 1024;  blk = b - 3840; }
    else               { src = Wo;  dst = WoB;               blk = b - 5888; }
    int idx = blk * 1024 + tid * 4;
    float4 v = *reinterpret_cast<const float4*>(src + idx);
    uint2 pk; pk.x = pack_bf16(v.x, v.y); pk.y = pack_bf16(v.z, v.w);
    *reinterpret_cast<uint2*>(dst + idx) = pk;
  } else {
    int row = b - 6912, c0 = tid * 4;
    int orow = 768 + row;
    float4 kv4 = *reinterpret_cast<const float4*>(lk + row * EMBED + c0);
    float4 vv4 = *reinterpret_cast<const float4*>(lv + row * EMBED + c0);
    *reinterpret_cast<float4*>(key_out + (size_t)orow * EMBED + c0) = kv4;
    *reinterpret_cast<float4*>(val_out + (size_t)orow * EMBED + c0) = vv4;
    uint2 pk, pv;
    pk.x = pack_bf16(kv4.x, kv4.y); pk.y = pack_bf16(kv4.z, kv4.w);
    pv.x = pack_bf16(vv4.x, vv4.y); pv.y = pack_bf16(vv4.z, vv4.w);
    *reinterpret_cast<uint2*>(k_bf + (size_t)orow * EMBED + c0) = pk;
    *reinterpret_cast<uint2*>(v_bf + (size_t)orow * EMBED + c0) = pv;
  }
}

// v_bf [kv][d] -> vT [d][kv], 64x64 LDS tiles.
__global__ __launch_bounds__(256) void transpose_kernel(
    const unsigned short* __restrict__ v_bf, unsigned short* __restrict__ vT) {
  __shared__ unsigned short T[64][72];
  int kt = blockIdx.x * 64, d0 = blockIdx.y * 64;
  int t = threadIdx.x;
  int r = t >> 3, c = (t & 7) * 8;
#pragma unroll
  for (int half = 0; half < 2; half++) {
    int kv = r + half * 32;
    short8 v = *reinterpret_cast<const short8*>(v_bf + (size_t)(kt + kv) * EMBED + d0 + c);
#pragma unroll
    for (int j = 0; j < 8; j++) T[c + j][kv] = (unsigned short)v[j];
  }
  __syncthreads();
#pragma unroll
  for (int half = 0; half < 2; half++) {
    int d = r + half * 32;
    *reinterpret_cast<short8*>(vT + (size_t)(d0 + d) * KV_LEN + kt + c) =
        *reinterpret_cast<const short8*>(&T[d][c]);
  }
}

// ---------------------------------------------------------------- QKV GEMM
// C[2816,3072] = X @ [Wq;Wkv]^T + bias.
// 128x128 tile, 8 WAVES (512 threads), wave tile 64x32 (2M x 4N),
// acc 4x2 = 32 regs/wave; 528 blocks, 16 waves/CU at 2 blocks/CU.
// LDS rows are 64 elem (128 B); 16B chunk index XOR-swizzled by (row&7);
// swizzle applied to the GLOBAL source column (gl2lds dest is lane-linear).
// Epilogue col routing:
//   [0,1024)    q_bf = bf16(C*QSCALE), rows >= 512 only (row - 512)
//   [1024,2048) key: orow remap, f32 key_out + bf16 k_bf
//   [2048,3072) value: orow remap, f32 val_out + bf16 v_bf
__global__ __launch_bounds__(512) void gemm_qkv(
    const __hip_bfloat16* __restrict__ A, const __hip_bfloat16* __restrict__ B,
    const float* __restrict__ bq, const float* __restrict__ bkv,
    float* __restrict__ key_out, float* __restrict__ val_out,
    __hip_bfloat16* __restrict__ q_bf, __hip_bfloat16* __restrict__ k_bf,
    __hip_bfloat16* __restrict__ v_bf) {
  __shared__ __align__(16) __hip_bfloat16 As[128 * 64];  // 16 KB
  __shared__ __align__(16) __hip_bfloat16 Bs[128 * 64];  // 16 KB
  const int K = EMBED;
  int tid = threadIdx.x;
  int wave = tid >> 6, lane = tid & 63, quad = lane >> 4, l16 = lane & 15;
  int wm = wave >> 2, wn = wave & 3;        // 2M x 4N
  int mbase = blockIdx.y * 128, nbase = blockIdx.x * 128;

  if (nbase + 128 <= 1024 && mbase + 128 <= 512) return;  // dead q rows

  int srow = tid >> 3;                       // 0..63
  int scol = ((tid & 7) ^ (srow & 7)) * 8;   // swizzled source column (elem)
  const __hip_bfloat16* aG = A + (size_t)(mbase + srow) * K + scol;
  const __hip_bfloat16* bG = B + (size_t)(nbase + srow) * K + scol;
  int swz = l16 & 7;

  f32x4 acc[4][2] = {};
  for (int kt = 0; kt < K; kt += 64) {
    gl2lds16(aG + kt, As + tid * 8);
    gl2lds16(aG + (size_t)64 * K + kt, As + (tid + 512) * 8);
    gl2lds16(bG + kt, Bs + tid * 8);
    gl2lds16(bG + (size_t)64 * K + kt, Bs + (tid + 512) * 8);
    __syncthreads();
#pragma unroll
    for (int ks = 0; ks < 2; ks++) {
      short8 af[4], bfr[2];
#pragma unroll
      for (int i = 0; i < 4; i++)
        af[i] = *reinterpret_cast<const short8*>(
            As + (wm * 64 + i * 16 + l16) * 64 + ((ks * 4 + quad) ^ swz) * 8);
#pragma unroll
      for (int j = 0; j < 2; j++)
        bfr[j] = *reinterpret_cast<const short8*>(
            Bs + (wn * 32 + j * 16 + l16) * 64 + ((ks * 4 + quad) ^ swz) * 8);
#pragma unroll
      for (int i = 0; i < 4; i++)
#pragma unroll
        for (int j = 0; j < 2; j++)
          acc[i][j] = __builtin_amdgcn_mfma_f32_16x16x32_bf16(af[i], bfr[j], acc[i][j], 0, 0, 0);
    }
    __syncthreads();
  }

#pragma unroll
  for (int i = 0; i < 4; i++) {
    int rb = mbase + wm * 64 + i * 16 + quad * 4;
#pragma unroll
    for (int j = 0; j < 2; j++) {
      int cg = nbase + wn * 32 + j * 16 + l16;
      float bv = (cg < 1024) ? bq[cg] : bkv[cg - 1024];
#pragma unroll
      for (int reg = 0; reg < 4; reg++) {
        int rg = rb + reg;
        float val = acc[i][j][reg] + bv;
        if (cg < 1024) {
          if (rg >= 512)
            q_bf[(size_t)(rg - 512) * 1024 + cg] = __float2bfloat16(val * QSCALE);
        } else {
          int orow = (rg < 768) ? rg : rg + 1024;
          if (cg < 2048) {
            int cc = cg - 1024;
            key_out[(size_t)orow * 1024 + cc] = val;
            k_bf[(size_t)orow * 1024 + cc] = __float2bfloat16(val);
          } else {
            int cc = cg - 2048;
            val_out[(size_t)orow * 1024 + cc] = val;
            v_bf[(size_t)orow * 1024 + cc] = __float2bfloat16(val);
          }
        }
      }
    }
  }
}

// ---------------------------------------------------------------- out GEMM
// out[2304,1024] = attn @ Wo^T + bo; 64x64 tile, BK=64, full K=1024 (no
// split-K; bias fused). 1D grid 576 = 8 XCD x 72, same-N-panel blocks
// grouped per XCD.
__global__ __launch_bounds__(256) void gemm_out(
    const __hip_bfloat16* __restrict__ A, const __hip_bfloat16* __restrict__ B,
    const float* __restrict__ bias, float* __restrict__ outf) {
  __shared__ __align__(16) __hip_bfloat16 As[64 * 64];
  __shared__ __align__(16) __hip_bfloat16 Bs[64 * 64];
  const int K = EMBED, N = EMBED;
  int tid = threadIdx.x;
  int wave = tid >> 6, lane = tid & 63, quad = lane >> 4, l16 = lane & 15;
  int wm = wave >> 1, wn = wave & 1;

  int lid = blockIdx.x;                 // 576 = 8 * 72
  int gsw = (lid & 7) * 72 + (lid >> 3);
  int bx = gsw / 36, by = gsw % 36;
  int mbase = by * 64, nbase = bx * 64;

  int srow = tid >> 3;
  int scol = ((tid & 7) ^ (srow & 7)) * 8;
  const __hip_bfloat16* aG = A + (size_t)(mbase + srow) * K + scol;
  const __hip_bfloat16* bG = B + (size_t)(nbase + srow) * K + scol;
  int swz = l16 & 7;

  f32x4 acc[2][2] = {};
  for (int kt = 0; kt < K; kt += 64) {
    gl2lds16(aG + kt, As + tid * 8);
    gl2lds16(aG + (size_t)32 * K + kt, As + (tid + 256) * 8);
    gl2lds16(bG + kt, Bs + tid * 8);
    gl2lds16(bG + (size_t)32 * K + kt, Bs + (tid + 256) * 8);
    __syncthreads();
#pragma unroll
    for (int ks = 0; ks < 2; ks++) {
      short8 af[2], bfr[2];
#pragma unroll
      for (int i = 0; i < 2; i++)
        af[i] = *reinterpret_cast<const short8*>(
            As + (wm * 32 + i * 16 + l16) * 64 + ((ks * 4 + quad) ^ swz) * 8);
#pragma unroll
      for (int j = 0; j < 2; j++)
        bfr[j] = *reinterpret_cast<const short8*>(
            Bs + (wn * 32 + j * 16 + l16) * 64 + ((ks * 4 + quad) ^ swz) * 8);
#pragma unroll
      for (int i = 0; i < 2; i++)
#pragma unroll
        for (int j = 0; j < 2; j++)
          acc[i][j] = __builtin_amdgcn_mfma_f32_16x16x32_bf16(af[i], bfr[j], acc[i][j], 0, 0, 0);
    }
    __syncthreads();
  }

#pragma unroll
  for (int i = 0; i < 2; i++) {
    int rb = mbase + wm * 32 + i * 16 + quad * 4;
#pragma unroll
    for (int j = 0; j < 2; j++) {
      int cg = nbase + wn * 32 + j * 16 + l16;
      float bv = bias[cg];
#pragma unroll
      for (int reg = 0; reg < 4; reg++)
        outf[(size_t)(rb + reg) * N + cg] = acc[i][j][reg] + bv;
    }
  }
}

// ---------------------------------------------------------------- attention
// Flash, KV-split x3, no online max (scores in log2 units, sigma~0.6; f32
// exp2 overflow needs ~200 sigma; underflow->0 is correct softmax).
// Block: 4 waves, one head, 128 q (32 q/wave). KVBLK=128 through LDS.
// 32x32x16 MFMAs, Q register-resident (B operand).
// S^T = mfma(K, Q): kv = (reg&3)+8*(reg>>2)+4*h2 + 32*kvs, q = lane&31.
// P never touches LDS: PV B-fragments (kv = 16c + 8*h2 + j) are assembled
// in-register from the S^T C-layout via one permlane32_swap pair per chunk.
// O^T = mfma(V^T, P): d = (reg&3)+8*(reg>>2)+4*h2 + 32*ds, q = lane&31.
//
// R15 (T15 att[2] double-pipeline): counters showed ~44% of cycles are
// dependency waits (VALU issue 34% + MFMA issue 22%, no pipe saturated).
// The kvs loop is now depth-2 software-pipelined with TWO named S tiles:
// QK(kvs+1)'s independent MFMA chain sits adjacent to SMPV(kvs)'s VALU
// chain so the scheduler can interleave. +16 VGPR (64->~80, cap 128: safe).
// setprio kept only on PV clusters so QK MFMAs can float.
//
// launch_bounds LOCKED at (256,4): unified VGPR+AGPR live set exceeds
// 512/6=85; (256,8)->64 and (256,6)->85 both spilled accumulators (R10:
// 1.2GB scratch, 420us; R7: 384MB, 155us). DO NOT raise. Spill tripwire:
// attn WRITE_SIZE must stay ~17MB (o_part+lsum).
__global__ __launch_bounds__(256, 4) void attn_kernel(
    const __hip_bfloat16* __restrict__ q_bf, const __hip_bfloat16* __restrict__ k_bf,
    const __hip_bfloat16* __restrict__ vT,
    __hip_bfloat16* __restrict__ o_part, float* __restrict__ lsum) {
  __shared__ __align__(16) __hip_bfloat16 Ks[128][72];   // [kv][d]  18.4 KB
  __shared__ __align__(16) __hip_bfloat16 VTs[64][136];  // [d][kv]  17.4 KB
  int tid = threadIdx.x;
  int w = tid >> 6, lane = tid & 63, l31 = lane & 31, h2 = lane >> 5;

  // 864 = 8 xcd * 6 groups * 18 qblocks. group g=(part*16+h); all 18
  // q-blocks of g share K/V -> pin them to xcd = g%8.
  int lid = blockIdx.x;
  int xcd = lid & 7, sfl = lid >> 3;
  int gi = sfl / 18, j = sfl - gi * 18;
  int g = gi * 8 + xcd;
  int part = g >> 4, h = g & 15;
  int qbase = j * 128;
  int qg = qbase + w * 32 + l31;

  short8 Qf[4];
#pragma unroll
  for (int ks = 0; ks < 4; ks++)
    Qf[ks] = *reinterpret_cast<const short8*>(
        q_bf + (size_t)qg * EMBED + h * HDIM + ks * 16 + h2 * 8);

  f32x16 ot[2] = {};
  float l_run = 0.f;

  // staging decompositions (256 threads, 16B each):
  // K rows (128 x 64 d):  chunk v: row = v*32 + (tid>>3), col = (tid&7)*8
  // VT rows (64 d x 128): chunk v: row = v*16 + (tid>>4), col = (tid&15)*8
  int krow = tid >> 3, kcol = (tid & 7) * 8;
  int vrow = tid >> 4, vcol = (tid & 15) * 8;
  const int kv0 = part * KV_PART;  // 10 tiles of 128

  // depth-2 pipeline pieces
  auto QK = [&](int kvs) -> f32x16 {
    f32x16 s = {};
#pragma unroll
    for (int ks = 0; ks < 4; ks++) {
      short8 ak = *reinterpret_cast<const short8*>(&Ks[kvs * 32 + l31][ks * 16 + h2 * 8]);
      s = __builtin_amdgcn_mfma_f32_32x32x16_bf16(ak, Qf[ks], s, 0, 0, 0);
    }
    return s;
  };
  auto SMPV = [&](const f32x16& s, int kvs) {
    // exp2 + pack; group gq holds kv = 32*kvs + 8*gq + 4*h2 + {0..3}
    unsigned u[4][2];
#pragma unroll
    for (int gq = 0; gq < 4; gq++) {
      float p0 = __builtin_amdgcn_exp2f(s[4 * gq + 0]);
      float p1 = __builtin_amdgcn_exp2f(s[4 * gq + 1]);
      float p2 = __builtin_amdgcn_exp2f(s[4 * gq + 2]);
      float p3 = __builtin_amdgcn_exp2f(s[4 * gq + 3]);
      l_run += (p0 + p1) + (p2 + p3);
      u[gq][0] = pack_bf16(p0, p1);
      u[gq][1] = pack_bf16(p2, p3);
    }
    // PV chunks c = 2*kvs + half (K=16 each, kv range [16c,16c+16))
#pragma unroll
    for (int half = 0; half < 2; half++) {
      int c = kvs * 2 + half;
      int gA = 2 * half, gB = 2 * half + 1;
      uint4 fr;
      plane_swap(u[gA][0], u[gB][0], h2, fr.x, fr.z);
      plane_swap(u[gA][1], u[gB][1], h2, fr.y, fr.w);
      short8 pf = __builtin_bit_cast(short8, fr);
      __builtin_amdgcn_s_setprio(1);
#pragma unroll
      for (int ds = 0; ds < 2; ds++) {
        short8 av = *reinterpret_cast<const short8*>(&VTs[ds * 32 + l31][c * 16 + h2 * 8]);
        ot[ds] = __builtin_amdgcn_mfma_f32_32x32x16_bf16(av, pf, ot[ds], 0, 0, 0);
      }
      __builtin_amdgcn_s_setprio(0);
    }
  };

  short8 kr[4], vr[4];
#pragma unroll
  for (int v = 0; v < 4; v++) {
    kr[v] = *reinterpret_cast<const short8*>(
        k_bf + (size_t)(kv0 + v * 32 + krow) * EMBED + h * HDIM + kcol);
    vr[v] = *reinterpret_cast<const short8*>(
        vT + (size_t)(h * HDIM + v * 16 + vrow) * KV_LEN + kv0 + vcol);
  }

  for (int kt = kv0; kt < kv0 + KV_PART; kt += 128) {
    __syncthreads();  // previous tile's LDS consumers done
#pragma unroll
    for (int v = 0; v < 4; v++) {
      *reinterpret_cast<short8*>(&Ks[v * 32 + krow][kcol]) = kr[v];
      *reinterpret_cast<short8*>(&VTs[v * 16 + vrow][vcol]) = vr[v];
    }
    __syncthreads();  // tile visible
    if (kt + 128 < kv0 + KV_PART) {  // prefetch next tile; completes under compute
#pragma unroll
      for (int v = 0; v < 4; v++) {
        kr[v] = *reinterpret_cast<const short8*>(
            k_bf + (size_t)(kt + 128 + v * 32 + krow) * EMBED + h * HDIM + kcol);
        vr[v] = *reinterpret_cast<const short8*>(
            vT + (size_t)(h * HDIM + v * 16 + vrow) * KV_LEN + kt + 128 + vcol);
      }
    }

    // depth-2 software pipeline over the 4 kvs sub-steps (T15):
    // QK(next) precedes SMPV(cur) so its MFMA chain interleaves with
    // cur's exp2/pack/swap VALU chain.
    {
      f32x16 sA = QK(0);
      f32x16 sB = QK(1);
      SMPV(sA, 0);
      sA = QK(2);
      SMPV(sB, 1);
      sB = QK(3);
      SMPV(sA, 2);
      SMPV(sB, 3);
    }
  }

  l_run += __shfl_xor(l_run, 32, 64);
  float inv = 1.0f / l_run;

  // O^T: d = (reg&3)+8*(reg>>2)+4*h2+32*ds, q = l31. 4 consecutive d per group.
  size_t orow = (size_t)part * Q_LEN + qg;
#pragma unroll
  for (int ds = 0; ds < 2; ds++)
#pragma unroll
    for (int gq = 0; gq < 4; gq++) {
      uint2 pk;
      pk.x = pack_bf16(ot[ds][4 * gq + 0] * inv, ot[ds][4 * gq + 1] * inv);
      pk.y = pack_bf16(ot[ds][4 * gq + 2] * inv, ot[ds][4 * gq + 3] * inv);
      *reinterpret_cast<uint2*>(
          o_part + orow * 1024 + h * HDIM + ds * 32 + gq * 8 + h2 * 4) = pk;
    }
  if (lane < 32)
    lsum[orow * NHEADS + h] = l_run;
}

// merge KV partitions (shared implicit max=0): O = sum_p l_p*o_hat_p / sum l_p
__global__ __launch_bounds__(256) void merge_kernel(
    const __hip_bfloat16* __restrict__ o_part, const float* __restrict__ lsum,
    __hip_bfloat16* __restrict__ attn_bf) {
  int q = blockIdx.x;
  int c = threadIdx.x * 4;
  int h = c >> 6;
  float wt[NPART], L = 0.f;
#pragma unroll
  for (int p = 0; p < NPART; p++) {
    wt[p] = lsum[((size_t)p * Q_LEN + q) * NHEADS + h];
    L += wt[p];
  }
  float invL = 1.0f / L;
  float acc[4] = {0.f, 0.f, 0.f, 0.f};
#pragma unroll
  for (int p = 0; p < NPART; p++) {
    __hip_bfloat16 v[4];
    *reinterpret_cast<uint2*>(v) =
        *reinterpret_cast<const uint2*>(o_part + ((size_t)p * Q_LEN + q) * 1024 + c);
#pragma unroll
    for (int jj = 0; jj < 4; jj++) acc[jj] += wt[p] * __bfloat162float(v[jj]);
  }
  uint2 pk;
  pk.x = pack_bf16(acc[0] * invL, acc[1] * invL);
  pk.y = pack_bf16(acc[2] * invL, acc[3] * invL);
  *reinterpret_cast<uint2*>(attn_bf + (size_t)q * 1024 + c) = pk;
}

// ---------------------------------------------------------------- launch

extern "C" void kernel_launch(void* const* d_in, const int* in_sizes, int n_in,
                              void* d_out, int out_size, void* d_ws, size_t ws_size,
                              hipStream_t stream) {
  const float* utt = (const float*)d_in[0];
  const float* rc  = (const float*)d_in[1];
  const float* mem = (const float*)d_in[2];
  const float* lk  = (const float*)d_in[3];
  const float* lv  = (const float*)d_in[4];
  const float* Wq  = (const float*)d_in[5];
  const float* bq  = (const float*)d_in[6];
  const float* Wkv = (const float*)d_in[7];
  const float* bkv = (const float*)d_in[8];
  const float* Wo  = (const float*)d_in[9];
  const float* bo  = (const float*)d_in[10];

  float* out_f   = (float*)d_out;                  // [2304,1024]
  float* key_out = out_f + Q_LEN * EMBED;          // [3840,1024]
  float* val_out = key_out + KV_LEN * EMBED;       // [3840,1024]

  char* ws = (char*)d_ws;
  size_t off = 0;
  __hip_bfloat16* X_bf   = (__hip_bfloat16*)(ws + off); off += (size_t)X_ROWS * EMBED * 2;
  __hip_bfloat16* WB_bf  = (__hip_bfloat16*)(ws + off); off += (size_t)3 * EMBED * EMBED * 2; // [Wq;Wkv]
  __hip_bfloat16* Wo_bf  = (__hip_bfloat16*)(ws + off); off += (size_t)EMBED * EMBED * 2;
  __hip_bfloat16* q_bf   = (__hip_bfloat16*)(ws + off); off += (size_t)Q_LEN * EMBED * 2;
  __hip_bfloat16* k_bf   = (__hip_bfloat16*)(ws + off); off += (size_t)KV_LEN * EMBED * 2;
  __hip_bfloat16* vT_bf  = (__hip_bfloat16*)(ws + off); off += (size_t)EMBED * KV_LEN * 2;
  __hip_bfloat16* o_part = (__hip_bfloat16*)(ws + off); off += (size_t)NPART * Q_LEN * EMBED * 2;
  // aliases (lifetimes disjoint): attn_bf over X_bf (X dead after QKV GEMM);
  // lsum over WB_bf (dead after QKV GEMM); v_bf over o_part (v_bf 7.9MB <=
  // o_part 14.2MB; v_bf dead after transpose, which runs before attn writes
  // o_part).
  __hip_bfloat16* attn_bf = X_bf;
  float* lsum = (float*)WB_bf;
  __hip_bfloat16* v_bf = o_part;
  (void)off; (void)ws_size; (void)in_sizes; (void)n_in; (void)out_size;

  prep_kernel<<<7936, 256, 0, stream>>>(mem, rc, utt, lk, lv, Wq, Wkv, Wo,
                                        X_bf, WB_bf, Wo_bf,
                                        key_out, val_out, k_bf, v_bf);
  gemm_qkv<<<dim3(3 * EMBED / 128, X_ROWS / 128), 512, 0, stream>>>(
      X_bf, WB_bf, bq, bkv, key_out, val_out, q_bf, k_bf, v_bf);
  transpose_kernel<<<dim3(KV_LEN / 64, EMBED / 64), 256, 0, stream>>>(
      (const unsigned short*)v_bf, (unsigned short*)vT_bf);
  attn_kernel<<<dim3((Q_LEN / 128) * NHEADS * NPART), 256, 0, stream>>>(
      q_bf, k_bf, vT_bf, o_part, lsum);
  merge_kernel<<<Q_LEN, 256, 0, stream>>>(o_part, lsum, attn_bf);
  gemm_out<<<576, 256, 0, stream>>>(attn_bf, Wo_bf, bo, out_f);
}

// Round 10
// 205.168 us; speedup vs baseline: 1.0120x; 1.0120x over previous
//
#include <hip/hip_runtime.h>
#include <hip/hip_bf16.h>

// Emformer attention, MI355X. Sizes fixed by the problem.
#define EMBED   1024
#define NHEADS  16
#define HDIM    64
#define U_LEN   2048
#define R_LEN   256
#define L_LEN   1024
#define M_LEN   512
#define Q_LEN   (U_LEN + R_LEN)                 // 2304
#define KV_LEN  (M_LEN + R_LEN + L_LEN + U_LEN) // 3840
#define X_ROWS  (M_LEN + R_LEN + U_LEN)         // 2816
#define NPART   3
#define KV_PART (KV_LEN / NPART)                // 1280

typedef __attribute__((ext_vector_type(8))) short short8;
typedef __attribute__((ext_vector_type(4))) float f32x4;
typedef __attribute__((ext_vector_type(16))) float f32x16;

#define QSCALE 0.180336880f  /* 0.125 * log2(e): exp() via exp2(), implicit max=0 */

__device__ __forceinline__ void gl2lds16(const __hip_bfloat16* g, __hip_bfloat16* l) {
  __builtin_amdgcn_global_load_lds(
      (const __attribute__((address_space(1))) unsigned int*)g,
      (__attribute__((address_space(3))) unsigned int*)l, 16, 0, 0);
}

// bf16 pack via v_cvt_pk_bf16_f32 (RNE, 1 instr).
__device__ __forceinline__ unsigned pack_bf16(float a, float b) {
  unsigned r;
  asm("v_cvt_pk_bf16_f32 %0, %1, %2" : "=v"(r) : "v"(a), "v"(b));
  return r;
}

// Exchange: lo = {lane<32: a(own), lane>=32: b(partner)};
//           hi = {lane<32: a(partner), lane>=32: b(own)}.
__device__ __forceinline__ void plane_swap(unsigned a, unsigned b, int h2,
                                           unsigned& lo, unsigned& hi) {
#if __has_builtin(__builtin_amdgcn_permlane32_swap)
  auto r = __builtin_amdgcn_permlane32_swap(a, b, false, false);
  lo = r[0]; hi = r[1];
#else
  unsigned s0 = h2 ? a : b;
  unsigned r0 = __shfl_xor(s0, 32, 64);
  lo = h2 ? r0 : a;
  hi = h2 ? b : r0;
#endif
}

// ---------------------------------------------------------------- prep
// One kernel, block-range dispatched:
// [0,2816)      build X = bf16([memory; rc; utterance])
// [2816,3840)   Wq  -> WB rows 0..1023
// [3840,5888)   Wkv -> WB rows 1024..3071
// [5888,6912)   Wo  -> Wo_bf
// [6912,7936)   left-context insert (f32 key/value rows 768..1791 + bf16 K)
// [7936,8960)   lv -> vT[d][768+kv] direct transpose (R16: transpose_kernel
//               deleted; block = one d-row, coalesced 8B vT writes, the
//               stride-4KB lv column reads are L2-absorbed, lv = 4MB)
__global__ __launch_bounds__(256) void prep_kernel(
    const float* __restrict__ mem, const float* __restrict__ rc,
    const float* __restrict__ utt, const float* __restrict__ lk,
    const float* __restrict__ lv, const float* __restrict__ Wq,
    const float* __restrict__ Wkv, const float* __restrict__ Wo,
    __hip_bfloat16* __restrict__ X, __hip_bfloat16* __restrict__ WB,
    __hip_bfloat16* __restrict__ WoB,
    float* __restrict__ key_out, float* __restrict__ val_out,
    __hip_bfloat16* __restrict__ k_bf, __hip_bfloat16* __restrict__ vT) {
  int b = blockIdx.x, tid = threadIdx.x;
  if (b < 2816) {
    int row = b, col = tid * 4;
    const float* src;
    if (row < M_LEN)              src = mem + row * EMBED;
    else if (row < M_LEN + R_LEN) src = rc + (row - M_LEN) * EMBED;
    else                          src = utt + (row - M_LEN - R_LEN) * EMBED;
    float4 v = *reinterpret_cast<const float4*>(src + col);
    uint2 pk; pk.x = pack_bf16(v.x, v.y); pk.y = pack_bf16(v.z, v.w);
    *reinterpret_cast<uint2*>(X + (size_t)row * EMBED + col) = pk;
  } else if (b < 6912) {
    const float* src; __hip_bfloat16* dst;
    int blk;
    if (b < 3840)      { src = Wq;  dst = WB;                blk = b - 2816; }
    else if (b < 5888) { src = Wkv; dst = WB + 1024 * 1024;  blk = b - 3840; }
    else               { src = Wo;  dst = WoB;               blk = b - 5888; }
    int idx = blk * 1024 + tid * 4;
    float4 v = *reinterpret_cast<const float4*>(src + idx);
    uint2 pk; pk.x = pack_bf16(v.x, v.y); pk.y = pack_bf16(v.z, v.w);
    *reinterpret_cast<uint2*>(dst + idx) = pk;
  } else if (b < 7936) {
    int row = b - 6912, c0 = tid * 4;
    int orow = 768 + row;
    float4 kv4 = *reinterpret_cast<const float4*>(lk + row * EMBED + c0);
    float4 vv4 = *reinterpret_cast<const float4*>(lv + row * EMBED + c0);
    *reinterpret_cast<float4*>(key_out + (size_t)orow * EMBED + c0) = kv4;
    *reinterpret_cast<float4*>(val_out + (size_t)orow * EMBED + c0) = vv4;
    uint2 pk;
    pk.x = pack_bf16(kv4.x, kv4.y); pk.y = pack_bf16(kv4.z, kv4.w);
    *reinterpret_cast<uint2*>(k_bf + (size_t)orow * EMBED + c0) = pk;
  } else {
    int d = b - 7936;            // vT row (feature)
    int kv = tid * 4;            // 4 lv rows per thread
    float v0 = lv[(size_t)(kv + 0) * EMBED + d];
    float v1 = lv[(size_t)(kv + 1) * EMBED + d];
    float v2 = lv[(size_t)(kv + 2) * EMBED + d];
    float v3 = lv[(size_t)(kv + 3) * EMBED + d];
    uint2 pk; pk.x = pack_bf16(v0, v1); pk.y = pack_bf16(v2, v3);
    *reinterpret_cast<uint2*>(vT + (size_t)d * KV_LEN + 768 + kv) = pk;
  }
}

// ---------------------------------------------------------------- QKV GEMM
// C[2816,3072] = X @ [Wq;Wkv]^T + bias.
// 128x128 tile, 8 WAVES (512 threads), wave tile 64x32 (2M x 4N),
// acc 4x2 = 32 regs/wave; 528 blocks, 16 waves/CU at 2 blocks/CU.
// LDS rows are 64 elem (128 B); 16B chunk index XOR-swizzled by (row&7);
// swizzle applied to the GLOBAL source column (gl2lds dest is lane-linear).
// Epilogue col routing:
//   [0,1024)    q_bf = bf16(C*QSCALE), rows >= 512 only (row - 512)
//   [1024,2048) key: orow remap, f32 key_out + bf16 k_bf
//   [2048,3072) value: orow remap, f32 val_out + bf16 written DIRECTLY into
//               vT[cc][orow..orow+3] (one uint2; the 4 acc regs are 4
//               consecutive kv rows at one feature; 768-remap boundary is
//               4-aligned so a group never straddles). R16: replaces the
//               row-major v_bf + separate transpose kernel.
__global__ __launch_bounds__(512) void gemm_qkv(
    const __hip_bfloat16* __restrict__ A, const __hip_bfloat16* __restrict__ B,
    const float* __restrict__ bq, const float* __restrict__ bkv,
    float* __restrict__ key_out, float* __restrict__ val_out,
    __hip_bfloat16* __restrict__ q_bf, __hip_bfloat16* __restrict__ k_bf,
    __hip_bfloat16* __restrict__ vT) {
  __shared__ __align__(16) __hip_bfloat16 As[128 * 64];  // 16 KB
  __shared__ __align__(16) __hip_bfloat16 Bs[128 * 64];  // 16 KB
  const int K = EMBED;
  int tid = threadIdx.x;
  int wave = tid >> 6, lane = tid & 63, quad = lane >> 4, l16 = lane & 15;
  int wm = wave >> 2, wn = wave & 3;        // 2M x 4N
  int mbase = blockIdx.y * 128, nbase = blockIdx.x * 128;

  if (nbase + 128 <= 1024 && mbase + 128 <= 512) return;  // dead q rows

  int srow = tid >> 3;                       // 0..63
  int scol = ((tid & 7) ^ (srow & 7)) * 8;   // swizzled source column (elem)
  const __hip_bfloat16* aG = A + (size_t)(mbase + srow) * K + scol;
  const __hip_bfloat16* bG = B + (size_t)(nbase + srow) * K + scol;
  int swz = l16 & 7;

  f32x4 acc[4][2] = {};
  for (int kt = 0; kt < K; kt += 64) {
    gl2lds16(aG + kt, As + tid * 8);
    gl2lds16(aG + (size_t)64 * K + kt, As + (tid + 512) * 8);
    gl2lds16(bG + kt, Bs + tid * 8);
    gl2lds16(bG + (size_t)64 * K + kt, Bs + (tid + 512) * 8);
    __syncthreads();
#pragma unroll
    for (int ks = 0; ks < 2; ks++) {
      short8 af[4], bfr[2];
#pragma unroll
      for (int i = 0; i < 4; i++)
        af[i] = *reinterpret_cast<const short8*>(
            As + (wm * 64 + i * 16 + l16) * 64 + ((ks * 4 + quad) ^ swz) * 8);
#pragma unroll
      for (int j = 0; j < 2; j++)
        bfr[j] = *reinterpret_cast<const short8*>(
            Bs + (wn * 32 + j * 16 + l16) * 64 + ((ks * 4 + quad) ^ swz) * 8);
#pragma unroll
      for (int i = 0; i < 4; i++)
#pragma unroll
        for (int j = 0; j < 2; j++)
          acc[i][j] = __builtin_amdgcn_mfma_f32_16x16x32_bf16(af[i], bfr[j], acc[i][j], 0, 0, 0);
    }
    __syncthreads();
  }

#pragma unroll
  for (int i = 0; i < 4; i++) {
    int rb = mbase + wm * 64 + i * 16 + quad * 4;
#pragma unroll
    for (int j = 0; j < 2; j++) {
      int cg = nbase + wn * 32 + j * 16 + l16;
      float bv = (cg < 1024) ? bq[cg] : bkv[cg - 1024];
      float v0 = acc[i][j][0] + bv, v1 = acc[i][j][1] + bv;
      float v2 = acc[i][j][2] + bv, v3 = acc[i][j][3] + bv;
      if (cg < 1024) {
        if (rb >= 512) {
          __hip_bfloat16* qd = q_bf + (size_t)(rb - 512) * 1024 + cg;
          qd[0]        = __float2bfloat16(v0 * QSCALE);
          qd[1024]     = __float2bfloat16(v1 * QSCALE);
          qd[2 * 1024] = __float2bfloat16(v2 * QSCALE);
          qd[3 * 1024] = __float2bfloat16(v3 * QSCALE);
        }
      } else {
        int orow = (rb < 768) ? rb : rb + 1024;  // 4-group never straddles 768
        if (cg < 2048) {
          int cc = cg - 1024;
          float* kd = key_out + (size_t)orow * 1024 + cc;
          kd[0] = v0; kd[1024] = v1; kd[2 * 1024] = v2; kd[3 * 1024] = v3;
          __hip_bfloat16* kb = k_bf + (size_t)orow * 1024 + cc;
          kb[0]        = __float2bfloat16(v0);
          kb[1024]     = __float2bfloat16(v1);
          kb[2 * 1024] = __float2bfloat16(v2);
          kb[3 * 1024] = __float2bfloat16(v3);
        } else {
          int cc = cg - 2048;
          float* vd = val_out + (size_t)orow * 1024 + cc;
          vd[0] = v0; vd[1024] = v1; vd[2 * 1024] = v2; vd[3 * 1024] = v3;
          uint2 pk; pk.x = pack_bf16(v0, v1); pk.y = pack_bf16(v2, v3);
          *reinterpret_cast<uint2*>(vT + (size_t)cc * KV_LEN + orow) = pk;
        }
      }
    }
  }
}

// ---------------------------------------------------------------- out GEMM
// out[2304,1024] = attn @ Wo^T + bo; 64x64 tile, BK=64, full K=1024 (no
// split-K; bias fused). 1D grid 576 = 8 XCD x 72, same-N-panel blocks
// grouped per XCD.
__global__ __launch_bounds__(256) void gemm_out(
    const __hip_bfloat16* __restrict__ A, const __hip_bfloat16* __restrict__ B,
    const float* __restrict__ bias, float* __restrict__ outf) {
  __shared__ __align__(16) __hip_bfloat16 As[64 * 64];
  __shared__ __align__(16) __hip_bfloat16 Bs[64 * 64];
  const int K = EMBED, N = EMBED;
  int tid = threadIdx.x;
  int wave = tid >> 6, lane = tid & 63, quad = lane >> 4, l16 = lane & 15;
  int wm = wave >> 1, wn = wave & 1;

  int lid = blockIdx.x;                 // 576 = 8 * 72
  int gsw = (lid & 7) * 72 + (lid >> 3);
  int bx = gsw / 36, by = gsw % 36;
  int mbase = by * 64, nbase = bx * 64;

  int srow = tid >> 3;
  int scol = ((tid & 7) ^ (srow & 7)) * 8;
  const __hip_bfloat16* aG = A + (size_t)(mbase + srow) * K + scol;
  const __hip_bfloat16* bG = B + (size_t)(nbase + srow) * K + scol;
  int swz = l16 & 7;

  f32x4 acc[2][2] = {};
  for (int kt = 0; kt < K; kt += 64) {
    gl2lds16(aG + kt, As + tid * 8);
    gl2lds16(aG + (size_t)32 * K + kt, As + (tid + 256) * 8);
    gl2lds16(bG + kt, Bs + tid * 8);
    gl2lds16(bG + (size_t)32 * K + kt, Bs + (tid + 256) * 8);
    __syncthreads();
#pragma unroll
    for (int ks = 0; ks < 2; ks++) {
      short8 af[2], bfr[2];
#pragma unroll
      for (int i = 0; i < 2; i++)
        af[i] = *reinterpret_cast<const short8*>(
            As + (wm * 32 + i * 16 + l16) * 64 + ((ks * 4 + quad) ^ swz) * 8);
#pragma unroll
      for (int j = 0; j < 2; j++)
        bfr[j] = *reinterpret_cast<const short8*>(
            Bs + (wn * 32 + j * 16 + l16) * 64 + ((ks * 4 + quad) ^ swz) * 8);
#pragma unroll
      for (int i = 0; i < 2; i++)
#pragma unroll
        for (int j = 0; j < 2; j++)
          acc[i][j] = __builtin_amdgcn_mfma_f32_16x16x32_bf16(af[i], bfr[j], acc[i][j], 0, 0, 0);
    }
    __syncthreads();
  }

#pragma unroll
  for (int i = 0; i < 2; i++) {
    int rb = mbase + wm * 32 + i * 16 + quad * 4;
#pragma unroll
    for (int j = 0; j < 2; j++) {
      int cg = nbase + wn * 32 + j * 16 + l16;
      float bv = bias[cg];
#pragma unroll
      for (int reg = 0; reg < 4; reg++)
        outf[(size_t)(rb + reg) * N + cg] = acc[i][j][reg] + bv;
    }
  }
}

// ---------------------------------------------------------------- attention
// (exact R14 body — R15's T15 double-pipeline spilled and regressed; attn is
// parked at ~55us: 6 structural experiments all neutral/negative.)
// Flash, KV-split x3, no online max (scores in log2 units, sigma~0.6; f32
// exp2 overflow needs ~200 sigma; underflow->0 is correct softmax).
// Block: 4 waves, one head, 128 q (32 q/wave). KVBLK=128 through LDS.
// 32x32x16 MFMAs, Q register-resident (B operand).
// S^T = mfma(K, Q): kv = (reg&3)+8*(reg>>2)+4*h2 + 32*kvs, q = lane&31.
// P never touches LDS: PV B-fragments (kv = 16c + 8*h2 + j) are assembled
// in-register from the S^T C-layout via one permlane32_swap pair per chunk.
// O^T = mfma(V^T, P): d = (reg&3)+8*(reg>>2)+4*h2 + 32*ds, q = lane&31.
//
// launch_bounds LOCKED at (256,4): unified VGPR+AGPR live set exceeds
// 512/6=85; (256,8)->64 and (256,6)->85 both spilled accumulators (R10:
// 1.2GB scratch, 420us; R7: 384MB, 155us). DO NOT raise. Spill tripwire:
// attn WRITE_SIZE must stay ~17MB (o_part+lsum).
__global__ __launch_bounds__(256, 4) void attn_kernel(
    const __hip_bfloat16* __restrict__ q_bf, const __hip_bfloat16* __restrict__ k_bf,
    const __hip_bfloat16* __restrict__ vT,
    __hip_bfloat16* __restrict__ o_part, float* __restrict__ lsum) {
  __shared__ __align__(16) __hip_bfloat16 Ks[128][72];   // [kv][d]  18.4 KB
  __shared__ __align__(16) __hip_bfloat16 VTs[64][136];  // [d][kv]  17.4 KB
  int tid = threadIdx.x;
  int w = tid >> 6, lane = tid & 63, l31 = lane & 31, h2 = lane >> 5;

  // 864 = 8 xcd * 6 groups * 18 qblocks. group g=(part*16+h); all 18
  // q-blocks of g share K/V -> pin them to xcd = g%8.
  int lid = blockIdx.x;
  int xcd = lid & 7, sfl = lid >> 3;
  int gi = sfl / 18, j = sfl - gi * 18;
  int g = gi * 8 + xcd;
  int part = g >> 4, h = g & 15;
  int qbase = j * 128;
  int qg = qbase + w * 32 + l31;

  short8 Qf[4];
#pragma unroll
  for (int ks = 0; ks < 4; ks++)
    Qf[ks] = *reinterpret_cast<const short8*>(
        q_bf + (size_t)qg * EMBED + h * HDIM + ks * 16 + h2 * 8);

  f32x16 ot[2] = {};
  float l_run = 0.f;

  // staging decompositions (256 threads, 16B each):
  // K rows (128 x 64 d):  chunk v: row = v*32 + (tid>>3), col = (tid&7)*8
  // VT rows (64 d x 128): chunk v: row = v*16 + (tid>>4), col = (tid&15)*8
  int krow = tid >> 3, kcol = (tid & 7) * 8;
  int vrow = tid >> 4, vcol = (tid & 15) * 8;
  const int kv0 = part * KV_PART;  // 10 tiles of 128

  short8 kr[4], vr[4];
#pragma unroll
  for (int v = 0; v < 4; v++) {
    kr[v] = *reinterpret_cast<const short8*>(
        k_bf + (size_t)(kv0 + v * 32 + krow) * EMBED + h * HDIM + kcol);
    vr[v] = *reinterpret_cast<const short8*>(
        vT + (size_t)(h * HDIM + v * 16 + vrow) * KV_LEN + kv0 + vcol);
  }

  for (int kt = kv0; kt < kv0 + KV_PART; kt += 128) {
    __syncthreads();  // previous tile's LDS consumers done
#pragma unroll
    for (int v = 0; v < 4; v++) {
      *reinterpret_cast<short8*>(&Ks[v * 32 + krow][kcol]) = kr[v];
      *reinterpret_cast<short8*>(&VTs[v * 16 + vrow][vcol]) = vr[v];
    }
    __syncthreads();  // tile visible
    if (kt + 128 < kv0 + KV_PART) {  // prefetch next tile; completes under compute
#pragma unroll
      for (int v = 0; v < 4; v++) {
        kr[v] = *reinterpret_cast<const short8*>(
            k_bf + (size_t)(kt + 128 + v * 32 + krow) * EMBED + h * HDIM + kcol);
        vr[v] = *reinterpret_cast<const short8*>(
            vT + (size_t)(h * HDIM + v * 16 + vrow) * KV_LEN + kt + 128 + vcol);
      }
    }

#pragma unroll
    for (int kvs = 0; kvs < 4; kvs++) {
      f32x16 s = {};
      __builtin_amdgcn_s_setprio(1);
#pragma unroll
      for (int ks = 0; ks < 4; ks++) {
        short8 ak = *reinterpret_cast<const short8*>(&Ks[kvs * 32 + l31][ks * 16 + h2 * 8]);
        s = __builtin_amdgcn_mfma_f32_32x32x16_bf16(ak, Qf[ks], s, 0, 0, 0);
      }
      __builtin_amdgcn_s_setprio(0);
      // exp2 + pack; group gq holds kv = 32*kvs + 8*gq + 4*h2 + {0..3}
      unsigned u[4][2];
#pragma unroll
      for (int gq = 0; gq < 4; gq++) {
        float p0 = __builtin_amdgcn_exp2f(s[4 * gq + 0]);
        float p1 = __builtin_amdgcn_exp2f(s[4 * gq + 1]);
        float p2 = __builtin_amdgcn_exp2f(s[4 * gq + 2]);
        float p3 = __builtin_amdgcn_exp2f(s[4 * gq + 3]);
        l_run += (p0 + p1) + (p2 + p3);
        u[gq][0] = pack_bf16(p0, p1);
        u[gq][1] = pack_bf16(p2, p3);
      }
      // PV chunks c = 2*kvs + half (K=16 each, kv range [16c,16c+16))
#pragma unroll
      for (int half = 0; half < 2; half++) {
        int c = kvs * 2 + half;
        int gA = 2 * half, gB = 2 * half + 1;
        uint4 fr;
        plane_swap(u[gA][0], u[gB][0], h2, fr.x, fr.z);
        plane_swap(u[gA][1], u[gB][1], h2, fr.y, fr.w);
        short8 pf = __builtin_bit_cast(short8, fr);
        __builtin_amdgcn_s_setprio(1);
#pragma unroll
        for (int ds = 0; ds < 2; ds++) {
          short8 av = *reinterpret_cast<const short8*>(&VTs[ds * 32 + l31][c * 16 + h2 * 8]);
          ot[ds] = __builtin_amdgcn_mfma_f32_32x32x16_bf16(av, pf, ot[ds], 0, 0, 0);
        }
        __builtin_amdgcn_s_setprio(0);
      }
    }
  }

  l_run += __shfl_xor(l_run, 32, 64);
  float inv = 1.0f / l_run;

  // O^T: d = (reg&3)+8*(reg>>2)+4*h2+32*ds, q = l31. 4 consecutive d per group.
  size_t orow = (size_t)part * Q_LEN + qg;
#pragma unroll
  for (int ds = 0; ds < 2; ds++)
#pragma unroll
    for (int gq = 0; gq < 4; gq++) {
      uint2 pk;
      pk.x = pack_bf16(ot[ds][4 * gq + 0] * inv, ot[ds][4 * gq + 1] * inv);
      pk.y = pack_bf16(ot[ds][4 * gq + 2] * inv, ot[ds][4 * gq + 3] * inv);
      *reinterpret_cast<uint2*>(
          o_part + orow * 1024 + h * HDIM + ds * 32 + gq * 8 + h2 * 4) = pk;
    }
  if (lane < 32)
    lsum[orow * NHEADS + h] = l_run;
}

// merge KV partitions (shared implicit max=0): O = sum_p l_p*o_hat_p / sum l_p
__global__ __launch_bounds__(256) void merge_kernel(
    const __hip_bfloat16* __restrict__ o_part, const float* __restrict__ lsum,
    __hip_bfloat16* __restrict__ attn_bf) {
  int q = blockIdx.x;
  int c = threadIdx.x * 4;
  int h = c >> 6;
  float wt[NPART], L = 0.f;
#pragma unroll
  for (int p = 0; p < NPART; p++) {
    wt[p] = lsum[((size_t)p * Q_LEN + q) * NHEADS + h];
    L += wt[p];
  }
  float invL = 1.0f / L;
  float acc[4] = {0.f, 0.f, 0.f, 0.f};
#pragma unroll
  for (int p = 0; p < NPART; p++) {
    __hip_bfloat16 v[4];
    *reinterpret_cast<uint2*>(v) =
        *reinterpret_cast<const uint2*>(o_part + ((size_t)p * Q_LEN + q) * 1024 + c);
#pragma unroll
    for (int jj = 0; jj < 4; jj++) acc[jj] += wt[p] * __bfloat162float(v[jj]);
  }
  uint2 pk;
  pk.x = pack_bf16(acc[0] * invL, acc[1] * invL);
  pk.y = pack_bf16(acc[2] * invL, acc[3] * invL);
  *reinterpret_cast<uint2*>(attn_bf + (size_t)q * 1024 + c) = pk;
}

// ---------------------------------------------------------------- launch

extern "C" void kernel_launch(void* const* d_in, const int* in_sizes, int n_in,
                              void* d_out, int out_size, void* d_ws, size_t ws_size,
                              hipStream_t stream) {
  const float* utt = (const float*)d_in[0];
  const float* rc  = (const float*)d_in[1];
  const float* mem = (const float*)d_in[2];
  const float* lk  = (const float*)d_in[3];
  const float* lv  = (const float*)d_in[4];
  const float* Wq  = (const float*)d_in[5];
  const float* bq  = (const float*)d_in[6];
  const float* Wkv = (const float*)d_in[7];
  const float* bkv = (const float*)d_in[8];
  const float* Wo  = (const float*)d_in[9];
  const float* bo  = (const float*)d_in[10];

  float* out_f   = (float*)d_out;                  // [2304,1024]
  float* key_out = out_f + Q_LEN * EMBED;          // [3840,1024]
  float* val_out = key_out + KV_LEN * EMBED;       // [3840,1024]

  char* ws = (char*)d_ws;
  size_t off = 0;
  __hip_bfloat16* X_bf   = (__hip_bfloat16*)(ws + off); off += (size_t)X_ROWS * EMBED * 2;
  __hip_bfloat16* WB_bf  = (__hip_bfloat16*)(ws + off); off += (size_t)3 * EMBED * EMBED * 2; // [Wq;Wkv]
  __hip_bfloat16* Wo_bf  = (__hip_bfloat16*)(ws + off); off += (size_t)EMBED * EMBED * 2;
  __hip_bfloat16* q_bf   = (__hip_bfloat16*)(ws + off); off += (size_t)Q_LEN * EMBED * 2;
  __hip_bfloat16* k_bf   = (__hip_bfloat16*)(ws + off); off += (size_t)KV_LEN * EMBED * 2;
  __hip_bfloat16* vT_bf  = (__hip_bfloat16*)(ws + off); off += (size_t)EMBED * KV_LEN * 2;
  __hip_bfloat16* o_part = (__hip_bfloat16*)(ws + off); off += (size_t)NPART * Q_LEN * EMBED * 2;
  // aliases (lifetimes disjoint): attn_bf over X_bf (X dead after QKV GEMM);
  // lsum over WB_bf (dead after QKV GEMM). v_bf no longer exists (vT is
  // written directly by prep + gemm_qkv; transpose kernel deleted in R16).
  __hip_bfloat16* attn_bf = X_bf;
  float* lsum = (float*)WB_bf;
  (void)off; (void)ws_size; (void)in_sizes; (void)n_in; (void)out_size;

  prep_kernel<<<8960, 256, 0, stream>>>(mem, rc, utt, lk, lv, Wq, Wkv, Wo,
                                        X_bf, WB_bf, Wo_bf,
                                        key_out, val_out, k_bf, vT_bf);
  gemm_qkv<<<dim3(3 * EMBED / 128, X_ROWS / 128), 512, 0, stream>>>(
      X_bf, WB_bf, bq, bkv, key_out, val_out, q_bf, k_bf, vT_bf);
  attn_kernel<<<dim3((Q_LEN / 128) * NHEADS * NPART), 256, 0, stream>>>(
      q_bf, k_bf, vT_bf, o_part, lsum);
  merge_kernel<<<Q_LEN, 256, 0, stream>>>(o_part, lsum, attn_bf);
  gemm_out<<<576, 256, 0, stream>>>(attn_bf, Wo_bf, bo, out_f);
}

// Round 11
// 197.960 us; speedup vs baseline: 1.0488x; 1.0364x over previous
//
#include <hip/hip_runtime.h>
#include <hip/hip_bf16.h>

// Emformer attention, MI355X. Sizes fixed by the problem.
#define EMBED   1024
#define NHEADS  16
#define HDIM    64
#define U_LEN   2048
#define R_LEN   256
#define L_LEN   1024
#define M_LEN   512
#define Q_LEN   (U_LEN + R_LEN)                 // 2304
#define KV_LEN  (M_LEN + R_LEN + L_LEN + U_LEN) // 3840
#define X_ROWS  (M_LEN + R_LEN + U_LEN)         // 2816
#define NPART   3
#define KV_PART (KV_LEN / NPART)                // 1280

typedef __attribute__((ext_vector_type(8))) short short8;
typedef __attribute__((ext_vector_type(4))) float f32x4;
typedef __attribute__((ext_vector_type(16))) float f32x16;

#define QSCALE 0.180336880f  /* 0.125 * log2(e): exp() via exp2(), implicit max=0 */

__device__ __forceinline__ void gl2lds16(const __hip_bfloat16* g, __hip_bfloat16* l) {
  __builtin_amdgcn_global_load_lds(
      (const __attribute__((address_space(1))) unsigned int*)g,
      (__attribute__((address_space(3))) unsigned int*)l, 16, 0, 0);
}

// bf16 pack via v_cvt_pk_bf16_f32 (RNE, 1 instr).
__device__ __forceinline__ unsigned pack_bf16(float a, float b) {
  unsigned r;
  asm("v_cvt_pk_bf16_f32 %0, %1, %2" : "=v"(r) : "v"(a), "v"(b));
  return r;
}

// Exchange: lo = {lane<32: a(own), lane>=32: b(partner)};
//           hi = {lane<32: a(partner), lane>=32: b(own)}.
__device__ __forceinline__ void plane_swap(unsigned a, unsigned b, int h2,
                                           unsigned& lo, unsigned& hi) {
#if __has_builtin(__builtin_amdgcn_permlane32_swap)
  auto r = __builtin_amdgcn_permlane32_swap(a, b, false, false);
  lo = r[0]; hi = r[1];
#else
  unsigned s0 = h2 ? a : b;
  unsigned r0 = __shfl_xor(s0, 32, 64);
  lo = h2 ? r0 : a;
  hi = h2 ? b : r0;
#endif
}

// ---------------------------------------------------------------- prep
// One kernel, block-range dispatched:
// [0,2816)      build X = bf16([memory; rc; utterance])
// [2816,3840)   Wq  -> WB rows 0..1023
// [3840,5888)   Wkv -> WB rows 1024..3071
// [5888,6912)   Wo  -> Wo_bf
// [6912,7936)   left-context insert (f32 key/value rows 768..1791 + bf16 K)
// [7936,8192)   lv -> vT[d][768+kv] via 64x64 LDS tile (R17: R16's column
//               reads were a 4KB-stride scatter, ~30MB over-fetch; this is
//               the deleted transpose_kernel's coalesced scheme, f32->bf16)
__global__ __launch_bounds__(256) void prep_kernel(
    const float* __restrict__ mem, const float* __restrict__ rc,
    const float* __restrict__ utt, const float* __restrict__ lk,
    const float* __restrict__ lv, const float* __restrict__ Wq,
    const float* __restrict__ Wkv, const float* __restrict__ Wo,
    __hip_bfloat16* __restrict__ X, __hip_bfloat16* __restrict__ WB,
    __hip_bfloat16* __restrict__ WoB,
    float* __restrict__ key_out, float* __restrict__ val_out,
    __hip_bfloat16* __restrict__ k_bf, __hip_bfloat16* __restrict__ vT) {
  int b = blockIdx.x, tid = threadIdx.x;
  if (b < 2816) {
    int row = b, col = tid * 4;
    const float* src;
    if (row < M_LEN)              src = mem + row * EMBED;
    else if (row < M_LEN + R_LEN) src = rc + (row - M_LEN) * EMBED;
    else                          src = utt + (row - M_LEN - R_LEN) * EMBED;
    float4 v = *reinterpret_cast<const float4*>(src + col);
    uint2 pk; pk.x = pack_bf16(v.x, v.y); pk.y = pack_bf16(v.z, v.w);
    *reinterpret_cast<uint2*>(X + (size_t)row * EMBED + col) = pk;
  } else if (b < 6912) {
    const float* src; __hip_bfloat16* dst;
    int blk;
    if (b < 3840)      { src = Wq;  dst = WB;                blk = b - 2816; }
    else if (b < 5888) { src = Wkv; dst = WB + 1024 * 1024;  blk = b - 3840; }
    else               { src = Wo;  dst = WoB;               blk = b - 5888; }
    int idx = blk * 1024 + tid * 4;
    float4 v = *reinterpret_cast<const float4*>(src + idx);
    uint2 pk; pk.x = pack_bf16(v.x, v.y); pk.y = pack_bf16(v.z, v.w);
    *reinterpret_cast<uint2*>(dst + idx) = pk;
  } else if (b < 7936) {
    int row = b - 6912, c0 = tid * 4;
    int orow = 768 + row;
    float4 kv4 = *reinterpret_cast<const float4*>(lk + row * EMBED + c0);
    float4 vv4 = *reinterpret_cast<const float4*>(lv + row * EMBED + c0);
    *reinterpret_cast<float4*>(key_out + (size_t)orow * EMBED + c0) = kv4;
    *reinterpret_cast<float4*>(val_out + (size_t)orow * EMBED + c0) = vv4;
    uint2 pk;
    pk.x = pack_bf16(kv4.x, kv4.y); pk.y = pack_bf16(kv4.z, kv4.w);
    *reinterpret_cast<uint2*>(k_bf + (size_t)orow * EMBED + c0) = pk;
  } else {
    // 64x64 tile transpose: lv[ktile+row][dtile+col] -> vT[dtile+d][768+ktile+kv]
    __shared__ __hip_bfloat16 T[64][72];
    int b2 = b - 7936;                 // 0..255
    int ktile = (b2 & 15) * 64;        // lv row (kv) tile
    int dtile = (b2 >> 4) * 64;        // feature tile
#pragma unroll
    for (int rr = 0; rr < 4; rr++) {
      int row = rr * 16 + (tid >> 4);  // 0..63
      int ch = (tid & 15) * 4;         // 0..60
      float4 v = *reinterpret_cast<const float4*>(
          lv + (size_t)(ktile + row) * EMBED + dtile + ch);
      T[ch + 0][row] = __float2bfloat16(v.x);
      T[ch + 1][row] = __float2bfloat16(v.y);
      T[ch + 2][row] = __float2bfloat16(v.z);
      T[ch + 3][row] = __float2bfloat16(v.w);
    }
    __syncthreads();
#pragma unroll
    for (int rr = 0; rr < 2; rr++) {
      int ci = rr * 256 + tid;         // 0..511
      int d = ci >> 3, kc = (ci & 7) * 8;
      *reinterpret_cast<short8*>(vT + (size_t)(dtile + d) * KV_LEN + 768 + ktile + kc) =
          *reinterpret_cast<const short8*>(&T[d][kc]);
    }
  }
}

// ---------------------------------------------------------------- QKV GEMM
// C[2816,3072] = X @ [Wq;Wkv]^T + bias.
// 128x128 tile, 8 WAVES (512 threads), wave tile 64x32 (2M x 4N),
// acc 4x2 = 32 regs/wave; 528 blocks, 16 waves/CU at 2 blocks/CU.
// LDS rows are 64 elem (128 B); 16B chunk index XOR-swizzled by (row&7);
// swizzle applied to the GLOBAL source column (gl2lds dest is lane-linear).
// Epilogue col routing:
//   [0,1024)    q_bf = bf16(C*QSCALE), rows >= 512 only (row - 512)
//   [1024,2048) key: orow remap, f32 key_out + bf16 k_bf
//   [2048,3072) value: orow remap, f32 val_out + bf16 written DIRECTLY into
//               vT[cc][orow..orow+3] (one uint2; the 4 acc regs are 4
//               consecutive kv rows at one feature; 768-remap boundary is
//               4-aligned so a group never straddles).
__global__ __launch_bounds__(512) void gemm_qkv(
    const __hip_bfloat16* __restrict__ A, const __hip_bfloat16* __restrict__ B,
    const float* __restrict__ bq, const float* __restrict__ bkv,
    float* __restrict__ key_out, float* __restrict__ val_out,
    __hip_bfloat16* __restrict__ q_bf, __hip_bfloat16* __restrict__ k_bf,
    __hip_bfloat16* __restrict__ vT) {
  __shared__ __align__(16) __hip_bfloat16 As[128 * 64];  // 16 KB
  __shared__ __align__(16) __hip_bfloat16 Bs[128 * 64];  // 16 KB
  const int K = EMBED;
  int tid = threadIdx.x;
  int wave = tid >> 6, lane = tid & 63, quad = lane >> 4, l16 = lane & 15;
  int wm = wave >> 2, wn = wave & 3;        // 2M x 4N
  int mbase = blockIdx.y * 128, nbase = blockIdx.x * 128;

  if (nbase + 128 <= 1024 && mbase + 128 <= 512) return;  // dead q rows

  int srow = tid >> 3;                       // 0..63
  int scol = ((tid & 7) ^ (srow & 7)) * 8;   // swizzled source column (elem)
  const __hip_bfloat16* aG = A + (size_t)(mbase + srow) * K + scol;
  const __hip_bfloat16* bG = B + (size_t)(nbase + srow) * K + scol;
  int swz = l16 & 7;

  f32x4 acc[4][2] = {};
  for (int kt = 0; kt < K; kt += 64) {
    gl2lds16(aG + kt, As + tid * 8);
    gl2lds16(aG + (size_t)64 * K + kt, As + (tid + 512) * 8);
    gl2lds16(bG + kt, Bs + tid * 8);
    gl2lds16(bG + (size_t)64 * K + kt, Bs + (tid + 512) * 8);
    __syncthreads();
#pragma unroll
    for (int ks = 0; ks < 2; ks++) {
      short8 af[4], bfr[2];
#pragma unroll
      for (int i = 0; i < 4; i++)
        af[i] = *reinterpret_cast<const short8*>(
            As + (wm * 64 + i * 16 + l16) * 64 + ((ks * 4 + quad) ^ swz) * 8);
#pragma unroll
      for (int j = 0; j < 2; j++)
        bfr[j] = *reinterpret_cast<const short8*>(
            Bs + (wn * 32 + j * 16 + l16) * 64 + ((ks * 4 + quad) ^ swz) * 8);
#pragma unroll
      for (int i = 0; i < 4; i++)
#pragma unroll
        for (int j = 0; j < 2; j++)
          acc[i][j] = __builtin_amdgcn_mfma_f32_16x16x32_bf16(af[i], bfr[j], acc[i][j], 0, 0, 0);
    }
    __syncthreads();
  }

#pragma unroll
  for (int i = 0; i < 4; i++) {
    int rb = mbase + wm * 64 + i * 16 + quad * 4;
#pragma unroll
    for (int j = 0; j < 2; j++) {
      int cg = nbase + wn * 32 + j * 16 + l16;
      float bv = (cg < 1024) ? bq[cg] : bkv[cg - 1024];
      float v0 = acc[i][j][0] + bv, v1 = acc[i][j][1] + bv;
      float v2 = acc[i][j][2] + bv, v3 = acc[i][j][3] + bv;
      if (cg < 1024) {
        if (rb >= 512) {
          __hip_bfloat16* qd = q_bf + (size_t)(rb - 512) * 1024 + cg;
          qd[0]        = __float2bfloat16(v0 * QSCALE);
          qd[1024]     = __float2bfloat16(v1 * QSCALE);
          qd[2 * 1024] = __float2bfloat16(v2 * QSCALE);
          qd[3 * 1024] = __float2bfloat16(v3 * QSCALE);
        }
      } else {
        int orow = (rb < 768) ? rb : rb + 1024;  // 4-group never straddles 768
        if (cg < 2048) {
          int cc = cg - 1024;
          float* kd = key_out + (size_t)orow * 1024 + cc;
          kd[0] = v0; kd[1024] = v1; kd[2 * 1024] = v2; kd[3 * 1024] = v3;
          __hip_bfloat16* kb = k_bf + (size_t)orow * 1024 + cc;
          kb[0]        = __float2bfloat16(v0);
          kb[1024]     = __float2bfloat16(v1);
          kb[2 * 1024] = __float2bfloat16(v2);
          kb[3 * 1024] = __float2bfloat16(v3);
        } else {
          int cc = cg - 2048;
          float* vd = val_out + (size_t)orow * 1024 + cc;
          vd[0] = v0; vd[1024] = v1; vd[2 * 1024] = v2; vd[3 * 1024] = v3;
          uint2 pk; pk.x = pack_bf16(v0, v1); pk.y = pack_bf16(v2, v3);
          *reinterpret_cast<uint2*>(vT + (size_t)cc * KV_LEN + orow) = pk;
        }
      }
    }
  }
}

// ---------------------------------------------------------------- out GEMM
// out[2304,1024] = attn @ Wo^T + bo; 64x64 tile, BK=64, full K=1024 (no
// split-K; bias fused). 1D grid 576 = 8 XCD x 72, same-N-panel blocks
// grouped per XCD.
__global__ __launch_bounds__(256) void gemm_out(
    const __hip_bfloat16* __restrict__ A, const __hip_bfloat16* __restrict__ B,
    const float* __restrict__ bias, float* __restrict__ outf) {
  __shared__ __align__(16) __hip_bfloat16 As[64 * 64];
  __shared__ __align__(16) __hip_bfloat16 Bs[64 * 64];
  const int K = EMBED, N = EMBED;
  int tid = threadIdx.x;
  int wave = tid >> 6, lane = tid & 63, quad = lane >> 4, l16 = lane & 15;
  int wm = wave >> 1, wn = wave & 1;

  int lid = blockIdx.x;                 // 576 = 8 * 72
  int gsw = (lid & 7) * 72 + (lid >> 3);
  int bx = gsw / 36, by = gsw % 36;
  int mbase = by * 64, nbase = bx * 64;

  int srow = tid >> 3;
  int scol = ((tid & 7) ^ (srow & 7)) * 8;
  const __hip_bfloat16* aG = A + (size_t)(mbase + srow) * K + scol;
  const __hip_bfloat16* bG = B + (size_t)(nbase + srow) * K + scol;
  int swz = l16 & 7;

  f32x4 acc[2][2] = {};
  for (int kt = 0; kt < K; kt += 64) {
    gl2lds16(aG + kt, As + tid * 8);
    gl2lds16(aG + (size_t)32 * K + kt, As + (tid + 256) * 8);
    gl2lds16(bG + kt, Bs + tid * 8);
    gl2lds16(bG + (size_t)32 * K + kt, Bs + (tid + 256) * 8);
    __syncthreads();
#pragma unroll
    for (int ks = 0; ks < 2; ks++) {
      short8 af[2], bfr[2];
#pragma unroll
      for (int i = 0; i < 2; i++)
        af[i] = *reinterpret_cast<const short8*>(
            As + (wm * 32 + i * 16 + l16) * 64 + ((ks * 4 + quad) ^ swz) * 8);
#pragma unroll
      for (int j = 0; j < 2; j++)
        bfr[j] = *reinterpret_cast<const short8*>(
            Bs + (wn * 32 + j * 16 + l16) * 64 + ((ks * 4 + quad) ^ swz) * 8);
#pragma unroll
      for (int i = 0; i < 2; i++)
#pragma unroll
        for (int j = 0; j < 2; j++)
          acc[i][j] = __builtin_amdgcn_mfma_f32_16x16x32_bf16(af[i], bfr[j], acc[i][j], 0, 0, 0);
    }
    __syncthreads();
  }

#pragma unroll
  for (int i = 0; i < 2; i++) {
    int rb = mbase + wm * 32 + i * 16 + quad * 4;
#pragma unroll
    for (int j = 0; j < 2; j++) {
      int cg = nbase + wn * 32 + j * 16 + l16;
      float bv = bias[cg];
#pragma unroll
      for (int reg = 0; reg < 4; reg++)
        outf[(size_t)(rb + reg) * N + cg] = acc[i][j][reg] + bv;
    }
  }
}

// ---------------------------------------------------------------- attention
// (exact R14 body — parked at ~54us after 6 structural experiments.)
// Flash, KV-split x3, no online max (scores in log2 units, sigma~0.6; f32
// exp2 overflow needs ~200 sigma; underflow->0 is correct softmax).
// Block: 4 waves, one head, 128 q (32 q/wave). KVBLK=128 through LDS.
// 32x32x16 MFMAs, Q register-resident (B operand).
// S^T = mfma(K, Q): kv = (reg&3)+8*(reg>>2)+4*h2 + 32*kvs, q = lane&31.
// P never touches LDS: PV B-fragments (kv = 16c + 8*h2 + j) are assembled
// in-register from the S^T C-layout via one permlane32_swap pair per chunk.
// O^T = mfma(V^T, P): d = (reg&3)+8*(reg>>2)+4*h2 + 32*ds, q = lane&31.
//
// launch_bounds LOCKED at (256,4): unified VGPR+AGPR live set exceeds
// 512/6=85; (256,8)->64 and (256,6)->85 both spilled accumulators (R10:
// 1.2GB scratch, 420us; R7: 384MB, 155us). DO NOT raise. Spill tripwire:
// attn WRITE_SIZE must stay ~17MB (o_part+lsum).
__global__ __launch_bounds__(256, 4) void attn_kernel(
    const __hip_bfloat16* __restrict__ q_bf, const __hip_bfloat16* __restrict__ k_bf,
    const __hip_bfloat16* __restrict__ vT,
    __hip_bfloat16* __restrict__ o_part, float* __restrict__ lsum) {
  __shared__ __align__(16) __hip_bfloat16 Ks[128][72];   // [kv][d]  18.4 KB
  __shared__ __align__(16) __hip_bfloat16 VTs[64][136];  // [d][kv]  17.4 KB
  int tid = threadIdx.x;
  int w = tid >> 6, lane = tid & 63, l31 = lane & 31, h2 = lane >> 5;

  // 864 = 8 xcd * 6 groups * 18 qblocks. group g=(part*16+h); all 18
  // q-blocks of g share K/V -> pin them to xcd = g%8.
  int lid = blockIdx.x;
  int xcd = lid & 7, sfl = lid >> 3;
  int gi = sfl / 18, j = sfl - gi * 18;
  int g = gi * 8 + xcd;
  int part = g >> 4, h = g & 15;
  int qbase = j * 128;
  int qg = qbase + w * 32 + l31;

  short8 Qf[4];
#pragma unroll
  for (int ks = 0; ks < 4; ks++)
    Qf[ks] = *reinterpret_cast<const short8*>(
        q_bf + (size_t)qg * EMBED + h * HDIM + ks * 16 + h2 * 8);

  f32x16 ot[2] = {};
  float l_run = 0.f;

  // staging decompositions (256 threads, 16B each):
  // K rows (128 x 64 d):  chunk v: row = v*32 + (tid>>3), col = (tid&7)*8
  // VT rows (64 d x 128): chunk v: row = v*16 + (tid>>4), col = (tid&15)*8
  int krow = tid >> 3, kcol = (tid & 7) * 8;
  int vrow = tid >> 4, vcol = (tid & 15) * 8;
  const int kv0 = part * KV_PART;  // 10 tiles of 128

  short8 kr[4], vr[4];
#pragma unroll
  for (int v = 0; v < 4; v++) {
    kr[v] = *reinterpret_cast<const short8*>(
        k_bf + (size_t)(kv0 + v * 32 + krow) * EMBED + h * HDIM + kcol);
    vr[v] = *reinterpret_cast<const short8*>(
        vT + (size_t)(h * HDIM + v * 16 + vrow) * KV_LEN + kv0 + vcol);
  }

  for (int kt = kv0; kt < kv0 + KV_PART; kt += 128) {
    __syncthreads();  // previous tile's LDS consumers done
#pragma unroll
    for (int v = 0; v < 4; v++) {
      *reinterpret_cast<short8*>(&Ks[v * 32 + krow][kcol]) = kr[v];
      *reinterpret_cast<short8*>(&VTs[v * 16 + vrow][vcol]) = vr[v];
    }
    __syncthreads();  // tile visible
    if (kt + 128 < kv0 + KV_PART) {  // prefetch next tile; completes under compute
#pragma unroll
      for (int v = 0; v < 4; v++) {
        kr[v] = *reinterpret_cast<const short8*>(
            k_bf + (size_t)(kt + 128 + v * 32 + krow) * EMBED + h * HDIM + kcol);
        vr[v] = *reinterpret_cast<const short8*>(
            vT + (size_t)(h * HDIM + v * 16 + vrow) * KV_LEN + kt + 128 + vcol);
      }
    }

#pragma unroll
    for (int kvs = 0; kvs < 4; kvs++) {
      f32x16 s = {};
      __builtin_amdgcn_s_setprio(1);
#pragma unroll
      for (int ks = 0; ks < 4; ks++) {
        short8 ak = *reinterpret_cast<const short8*>(&Ks[kvs * 32 + l31][ks * 16 + h2 * 8]);
        s = __builtin_amdgcn_mfma_f32_32x32x16_bf16(ak, Qf[ks], s, 0, 0, 0);
      }
      __builtin_amdgcn_s_setprio(0);
      // exp2 + pack; group gq holds kv = 32*kvs + 8*gq + 4*h2 + {0..3}
      unsigned u[4][2];
#pragma unroll
      for (int gq = 0; gq < 4; gq++) {
        float p0 = __builtin_amdgcn_exp2f(s[4 * gq + 0]);
        float p1 = __builtin_amdgcn_exp2f(s[4 * gq + 1]);
        float p2 = __builtin_amdgcn_exp2f(s[4 * gq + 2]);
        float p3 = __builtin_amdgcn_exp2f(s[4 * gq + 3]);
        l_run += (p0 + p1) + (p2 + p3);
        u[gq][0] = pack_bf16(p0, p1);
        u[gq][1] = pack_bf16(p2, p3);
      }
      // PV chunks c = 2*kvs + half (K=16 each, kv range [16c,16c+16))
#pragma unroll
      for (int half = 0; half < 2; half++) {
        int c = kvs * 2 + half;
        int gA = 2 * half, gB = 2 * half + 1;
        uint4 fr;
        plane_swap(u[gA][0], u[gB][0], h2, fr.x, fr.z);
        plane_swap(u[gA][1], u[gB][1], h2, fr.y, fr.w);
        short8 pf = __builtin_bit_cast(short8, fr);
        __builtin_amdgcn_s_setprio(1);
#pragma unroll
        for (int ds = 0; ds < 2; ds++) {
          short8 av = *reinterpret_cast<const short8*>(&VTs[ds * 32 + l31][c * 16 + h2 * 8]);
          ot[ds] = __builtin_amdgcn_mfma_f32_32x32x16_bf16(av, pf, ot[ds], 0, 0, 0);
        }
        __builtin_amdgcn_s_setprio(0);
      }
    }
  }

  l_run += __shfl_xor(l_run, 32, 64);
  float inv = 1.0f / l_run;

  // O^T: d = (reg&3)+8*(reg>>2)+4*h2+32*ds, q = l31. 4 consecutive d per group.
  size_t orow = (size_t)part * Q_LEN + qg;
#pragma unroll
  for (int ds = 0; ds < 2; ds++)
#pragma unroll
    for (int gq = 0; gq < 4; gq++) {
      uint2 pk;
      pk.x = pack_bf16(ot[ds][4 * gq + 0] * inv, ot[ds][4 * gq + 1] * inv);
      pk.y = pack_bf16(ot[ds][4 * gq + 2] * inv, ot[ds][4 * gq + 3] * inv);
      *reinterpret_cast<uint2*>(
          o_part + orow * 1024 + h * HDIM + ds * 32 + gq * 8 + h2 * 4) = pk;
    }
  if (lane < 32)
    lsum[orow * NHEADS + h] = l_run;
}

// merge KV partitions (shared implicit max=0): O = sum_p l_p*o_hat_p / sum l_p
__global__ __launch_bounds__(256) void merge_kernel(
    const __hip_bfloat16* __restrict__ o_part, const float* __restrict__ lsum,
    __hip_bfloat16* __restrict__ attn_bf) {
  int q = blockIdx.x;
  int c = threadIdx.x * 4;
  int h = c >> 6;
  float wt[NPART], L = 0.f;
#pragma unroll
  for (int p = 0; p < NPART; p++) {
    wt[p] = lsum[((size_t)p * Q_LEN + q) * NHEADS + h];
    L += wt[p];
  }
  float invL = 1.0f / L;
  float acc[4] = {0.f, 0.f, 0.f, 0.f};
#pragma unroll
  for (int p = 0; p < NPART; p++) {
    __hip_bfloat16 v[4];
    *reinterpret_cast<uint2*>(v) =
        *reinterpret_cast<const uint2*>(o_part + ((size_t)p * Q_LEN + q) * 1024 + c);
#pragma unroll
    for (int jj = 0; jj < 4; jj++) acc[jj] += wt[p] * __bfloat162float(v[jj]);
  }
  uint2 pk;
  pk.x = pack_bf16(acc[0] * invL, acc[1] * invL);
  pk.y = pack_bf16(acc[2] * invL, acc[3] * invL);
  *reinterpret_cast<uint2*>(attn_bf + (size_t)q * 1024 + c) = pk;
}

// ---------------------------------------------------------------- launch

extern "C" void kernel_launch(void* const* d_in, const int* in_sizes, int n_in,
                              void* d_out, int out_size, void* d_ws, size_t ws_size,
                              hipStream_t stream) {
  const float* utt = (const float*)d_in[0];
  const float* rc  = (const float*)d_in[1];
  const float* mem = (const float*)d_in[2];
  const float* lk  = (const float*)d_in[3];
  const float* lv  = (const float*)d_in[4];
  const float* Wq  = (const float*)d_in[5];
  const float* bq  = (const float*)d_in[6];
  const float* Wkv = (const float*)d_in[7];
  const float* bkv = (const float*)d_in[8];
  const float* Wo  = (const float*)d_in[9];
  const float* bo  = (const float*)d_in[10];

  float* out_f   = (float*)d_out;                  // [2304,1024]
  float* key_out = out_f + Q_LEN * EMBED;          // [3840,1024]
  float* val_out = key_out + KV_LEN * EMBED;       // [3840,1024]

  char* ws = (char*)d_ws;
  size_t off = 0;
  __hip_bfloat16* X_bf   = (__hip_bfloat16*)(ws + off); off += (size_t)X_ROWS * EMBED * 2;
  __hip_bfloat16* WB_bf  = (__hip_bfloat16*)(ws + off); off += (size_t)3 * EMBED * EMBED * 2; // [Wq;Wkv]
  __hip_bfloat16* Wo_bf  = (__hip_bfloat16*)(ws + off); off += (size_t)EMBED * EMBED * 2;
  __hip_bfloat16* q_bf   = (__hip_bfloat16*)(ws + off); off += (size_t)Q_LEN * EMBED * 2;
  __hip_bfloat16* k_bf   = (__hip_bfloat16*)(ws + off); off += (size_t)KV_LEN * EMBED * 2;
  __hip_bfloat16* vT_bf  = (__hip_bfloat16*)(ws + off); off += (size_t)EMBED * KV_LEN * 2;
  __hip_bfloat16* o_part = (__hip_bfloat16*)(ws + off); off += (size_t)NPART * Q_LEN * EMBED * 2;
  // aliases (lifetimes disjoint): attn_bf over X_bf (X dead after QKV GEMM);
  // lsum over WB_bf (dead after QKV GEMM).
  __hip_bfloat16* attn_bf = X_bf;
  float* lsum = (float*)WB_bf;
  (void)off; (void)ws_size; (void)in_sizes; (void)n_in; (void)out_size;

  prep_kernel<<<8192, 256, 0, stream>>>(mem, rc, utt, lk, lv, Wq, Wkv, Wo,
                                        X_bf, WB_bf, Wo_bf,
                                        key_out, val_out, k_bf, vT_bf);
  gemm_qkv<<<dim3(3 * EMBED / 128, X_ROWS / 128), 512, 0, stream>>>(
      X_bf, WB_bf, bq, bkv, key_out, val_out, q_bf, k_bf, vT_bf);
  attn_kernel<<<dim3((Q_LEN / 128) * NHEADS * NPART), 256, 0, stream>>>(
      q_bf, k_bf, vT_bf, o_part, lsum);
  merge_kernel<<<Q_LEN, 256, 0, stream>>>(o_part, lsum, attn_bf);
  gemm_out<<<576, 256, 0, stream>>>(attn_bf, Wo_bf, bo, out_f);
}